// Round 11
// baseline (1376.871 us; speedup 1.0000x reference)
//
#include <hip/hip_runtime.h>

#define NB 128
#define NS 256
#define NI 64
#define NH 128
#define NL 64
#define NG 384  // 3*NH

typedef _Float16 f16;
typedef __attribute__((ext_vector_type(2))) _Float16 f16x2;

__device__ __forceinline__ float fast_tanh(float x) {
    float e = __expf(2.0f * x);
    return 1.0f - 2.0f / (e + 1.0f);
}
__device__ __forceinline__ float fast_sig(float x) {
    return 1.0f / (1.0f + __expf(-x));
}
__device__ __forceinline__ float red1(float a) {  // epilogue pair-reduce
    int ai = __builtin_bit_cast(int, a);
    int bi = __builtin_amdgcn_update_dpp(0, ai, 0xB1, 0xF, 0xF, true);
    return a + __builtin_bit_cast(float, bi);
}
__device__ __forceinline__ float fdot2(f16x2 a, f16x2 b, float c) {
#if __has_builtin(__builtin_amdgcn_fdot2)
    return __builtin_amdgcn_fdot2(a, b, c, false);
#else
    return c + (float)a.x * (float)b.x + (float)a.y * (float)b.y;
#endif
}
__device__ __forceinline__ f16x2 bcu(int u) {
    return __builtin_bit_cast(f16x2, u);
}
__device__ __forceinline__ int pack2h(float x, float y) {
    f16x2 v; v.x = (f16)x; v.y = (f16)y;
    return __builtin_bit_cast(int, v);
}
// LDS-only workgroup barrier (no vmcnt drain: global prefetch stays in flight)
__device__ __forceinline__ void sync_lds() {
    asm volatile("s_waitcnt lgkmcnt(0)" ::: "memory");
    __builtin_amdgcn_s_barrier();
    asm volatile("" ::: "memory");
}

// ---- f16 weight tables (pre-rounded once by prep_kernel) ----
__device__ __align__(16) f16 g_W1h[NH * NH];
__device__ __align__(16) f16 g_W2h[NH * NH];
__device__ __align__(16) f16 g_W12h[NH * NH];
__device__ __align__(16) f16 g_Whhh[3 * NH * NH];
__device__ __align__(16) f16 g_Whh2h[3 * NH * NH];
__device__ float g_w1b2[NH];
__device__ float g_whhb2[3 * NH];
__device__ float g_gxfb[(size_t)NS * NB * NG];  // gx fallback if ws too small

// ---------------------------------------------------------------------------
// GX precompute: gx[s][b][j] = b_ih[j] + sum_c x[b][s][c] * W_ih[j][c]
// ---------------------------------------------------------------------------
__global__ __launch_bounds__(384)
void gx_kernel(const float* __restrict__ x, const float* __restrict__ W_ih,
               const float* __restrict__ b_ih, float* __restrict__ gx)
{
    const int s = blockIdx.x;
    const int j = threadIdx.x;
    __shared__ __align__(16) float xs[NB * NI];
    for (int idx = j; idx < NB * NI; idx += 384) {
        int bb = idx >> 6, cc = idx & 63;
        xs[idx] = x[(bb * NS + s) * NI + cc];
    }
    float w[64];
#pragma unroll
    for (int c = 0; c < 64; c += 4)
        *(float4*)&w[c] = *(const float4*)&W_ih[j * NI + c];
    const float bj = b_ih[j];
    __syncthreads();
    for (int bb = 0; bb < NB; bb++) {
        const float* xr = xs + bb * NI;
        float a0 = 0.f, a1 = 0.f, a2 = 0.f, a3 = 0.f;
#pragma unroll
        for (int c = 0; c < 64; c += 4) {
            a0 = fmaf(w[c + 0], xr[c + 0], a0);
            a1 = fmaf(w[c + 1], xr[c + 1], a1);
            a2 = fmaf(w[c + 2], xr[c + 2], a2);
            a3 = fmaf(w[c + 3], xr[c + 3], a3);
        }
        gx[((size_t)s * NB + bb) * NG + j] = ((a0 + a1) + (a2 + a3)) + bj;
    }
}

// ---------------------------------------------------------------------------
// Setup (fp32 math, then round to f16): W12=W1@W2, Whh2=Whh@W2, W1b2, Whhb2,
// plus f16 copies of W1, W2, Whh.
// ---------------------------------------------------------------------------
__global__ __launch_bounds__(128)
void prep_kernel(const float* __restrict__ W1, const float* __restrict__ Whh,
                 const float* __restrict__ W2, const float* __restrict__ b2)
{
    const int i = blockIdx.x;   // 0..511
    const int j = threadIdx.x;  // 0..127
    __shared__ float rowA[NH];
    __shared__ float red[NH];
    const float* src = (i < NH) ? (W1 + i * NH) : (Whh + (size_t)(i - NH) * NH);
    rowA[j] = src[j];
    __syncthreads();
    float acc = 0.f;
    for (int k = 0; k < NH; k++) acc = fmaf(rowA[k], W2[k * NH + j], acc);
    if (i < NH) {
        g_W12h[i * NH + j] = (f16)acc;
        g_W1h[i * NH + j]  = (f16)rowA[j];
        g_W2h[i * NH + j]  = (f16)W2[i * NH + j];
    } else {
        g_Whh2h[(size_t)(i - NH) * NH + j] = (f16)acc;
        g_Whhh[(size_t)(i - NH) * NH + j]  = (f16)rowA[j];
    }
    red[j] = rowA[j] * b2[j];
    __syncthreads();
    for (int off = 64; off > 0; off >>= 1) {
        if (j < off) red[j] += red[j + off];
        __syncthreads();
    }
    if (j == 0) {
        if (i < NH) g_w1b2[i] = red[0];
        else        g_whhb2[i - NH] = red[0];
    }
}

// ---------------------------------------------------------------------------
// bpermute-broadcast matvec: PK = per-lane u32 pack (elements 2L,2L+1).
// ds_bpermute(4k, PK) broadcasts lane k's pack to all lanes (register
// crossbar — no LDS memory, no barrier, lgkmcnt-pipelined).
// Weights: int[64] per row, literal indices only.
// ---------------------------------------------------------------------------
#define BDOT(WA, WB, PK, O0, O1)                                               \
    {                                                                          \
        float a0_ = 0.f, a1_ = 0.f, b0_ = 0.f, b1_ = 0.f;                      \
        _Pragma("unroll") for (int k = 0; k < 64; k += 2)                      \
        {                                                                      \
            int v0_ = __builtin_amdgcn_ds_bpermute(4 * k, (PK));               \
            int v1_ = __builtin_amdgcn_ds_bpermute(4 * k + 4, (PK));           \
            a0_ = fdot2(bcu(WA[k]), bcu(v0_), a0_);                            \
            b0_ = fdot2(bcu(WB[k]), bcu(v0_), b0_);                            \
            a1_ = fdot2(bcu(WA[k + 1]), bcu(v1_), a1_);                        \
            b1_ = fdot2(bcu(WB[k + 1]), bcu(v1_), b1_);                        \
        }                                                                      \
        O0 = a0_ + a1_;                                                        \
        O1 = b0_ + b1_;                                                        \
    }

// load one full f16 row (128 = 256B) into int[64]
#define LOADROW(DST, BASE)                                                     \
    {                                                                          \
        const uint4* p_ = (const uint4*)(BASE);                                \
        _Pragma("unroll") for (int j_ = 0; j_ < 16; j_++)                      \
        {                                                                      \
            uint4 v_ = p_[j_];                                                 \
            DST[4 * j_ + 0] = v_.x; DST[4 * j_ + 1] = v_.y;                    \
            DST[4 * j_ + 2] = v_.z; DST[4 * j_ + 3] = v_.w;                    \
        }                                                                      \
    }

#define PIN2(A, B)                                                             \
    _Pragma("unroll") for (int i_ = 0; i_ < 64; i_++)                          \
    { asm volatile("" : "+v"(A[i_]), "+v"(B[i_])); }

// ---------------------------------------------------------------------------
// Main recurrence: 1 WG / batch element, 512 threads = 8 waves (2/SIMD).
// w0: st1 (W1 from swizzled LDS) + barrier-free bpermute chain (W12 regs).
// w1: W2 -> hB; owns h; GRU. w2-4: Whh_g·h (chain window). w5-7: Whh2_g·Spp.
// 3 barriers/step: B_h -> B2 (Spp+GA) -> B_fin (GS).
// ---------------------------------------------------------------------------
__global__ __launch_bounds__(512, 2)
void rnn_kernel(const float* __restrict__ times, const float* __restrict__ b_hh,
                const float* __restrict__ b1, const float* __restrict__ b2,
                const float* __restrict__ W_mean, const float* __restrict__ b_mean,
                const float* __restrict__ W_logvar, const float* __restrict__ b_logvar,
                const float* __restrict__ gx,
                float* __restrict__ out)
{
    const int b = blockIdx.x;
    const int t = threadIdx.x;   // 0..511
    const int w = t >> 6;        // wave 0..7
    const int L = t & 63;        // lane
    const int r0 = 2 * L, r1 = 2 * L + 1;
    const int key = L & 7;       // sW1 swizzle key (= (r0>>1)&7 = (r1>>1)&7)

    __shared__ float shT[NS];
    __shared__ int shHpk[64];        // h pack (f16x2 rows 2L,2L+1)
    __shared__ int shSpp[64];        // (S+S2) pack
    __shared__ float2 shGA[3][64];   // Whh_g · h
    __shared__ float2 shGS[3][64];   // Whh2_g · Spp
    __shared__ __align__(16) unsigned int sW1[NH * 64];  // 32KB swizzled W1
    __shared__ __align__(16) float shHfl[NH];

    // stage sW1 (chunk j of row r stored at j ^ ((r>>1)&7)) — conflict-free reads
    for (int idx = t; idx < NH * 16; idx += 512) {
        const int r = idx >> 4, j = idx & 15;
        uint4 v = ((const uint4*)g_W1h)[idx];
        ((uint4*)sW1)[(r << 4) | (j ^ ((r >> 1) & 7))] = v;
    }
    for (int i = t; i < NS; i += 512) shT[i] = times[i];
    if (t < 64) shHpk[t] = 0;
    __syncthreads();

    // ---- per-wave persistent weight rows (<=128 u32) ----
    int wa[64], wb[64];
    if (w == 0) {
        LOADROW(wa, g_W12h + r0 * NH);
        LOADROW(wb, g_W12h + r1 * NH);
    } else if (w == 1) {
        LOADROW(wa, g_W2h + r0 * NH);
        LOADROW(wb, g_W2h + r1 * NH);
    } else if (w <= 4) {
        const int g = w - 2;
        LOADROW(wa, g_Whhh + (size_t)(g * NH + r0) * NH);
        LOADROW(wb, g_Whhh + (size_t)(g * NH + r1) * NH);
    } else {
        const int g = w - 5;
        LOADROW(wa, g_Whh2h + (size_t)(g * NH + r0) * NH);
        LOADROW(wb, g_Whh2h + (size_t)(g * NH + r1) * NH);
    }

    const float b1r0 = b1[r0], b1r1 = b1[r1];
    const float w1b20 = g_w1b2[r0], w1b21 = g_w1b2[r1];
    const float b20 = b2[r0], b21 = b2[r1];
    // w1 GRU scalars
    float bhr0 = 0, bhr1 = 0, bhz0 = 0, bhz1 = 0, bhn0 = 0, bhn1 = 0;
    float sbr0 = 0, sbr1 = 0, sbz0 = 0, sbz1 = 0, sbn0 = 0, sbn1 = 0;
    if (w == 1) {
        bhr0 = b_hh[r0]; bhr1 = b_hh[r1];
        bhz0 = b_hh[NH + r0]; bhz1 = b_hh[NH + r1];
        bhn0 = b_hh[2 * NH + r0]; bhn1 = b_hh[2 * NH + r1];
        sbr0 = g_whhb2[r0]; sbr1 = g_whhb2[r1];
        sbz0 = g_whhb2[NH + r0]; sbz1 = g_whhb2[NH + r1];
        sbn0 = g_whhb2[2 * NH + r0]; sbn1 = g_whhb2[2 * NH + r1];
    }

    float h0 = 0.f, h1 = 0.f;               // live in w1
    float2 gxr, gxz, gxn;                   // w1 gx prefetch

    for (int si = 0; si < NS; ++si) {
        const int seq = NS - 1 - si;
        const float dt = (si == 0) ? 0.f : (shT[seq] - shT[seq + 1]);
        const float dts = 0.5f * dt;   // substep dt (N_SUB=2)
        const float a2c = 0.5f * dts;
        const float a6 = dts * (1.f / 6.f);

        sync_lds();  // ===== B_h: h pack from previous iteration visible =====

        if (w == 0) {
            PIN2(wa, wb);
            const int hpk = shHpk[L];
            // ---- st1: z1a = W1 h + b1 (W1 streamed from swizzled LDS) ----
            float z1a0, z1a1;
            {
                float a0_ = 0.f, a1_ = 0.f, c0_ = 0.f, c1_ = 0.f;
#pragma unroll
                for (int c = 0; c < 8; c++) {
                    uint4 va  = ((const uint4*)sW1)[(r0 << 4) | ((2 * c) ^ key)];
                    uint4 va2 = ((const uint4*)sW1)[(r0 << 4) | ((2 * c + 1) ^ key)];
                    uint4 vb  = ((const uint4*)sW1)[(r1 << 4) | ((2 * c) ^ key)];
                    uint4 vb2 = ((const uint4*)sW1)[(r1 << 4) | ((2 * c + 1) ^ key)];
                    int p0 = __builtin_amdgcn_ds_bpermute(4 * (8 * c + 0), hpk);
                    int p1 = __builtin_amdgcn_ds_bpermute(4 * (8 * c + 1), hpk);
                    int p2 = __builtin_amdgcn_ds_bpermute(4 * (8 * c + 2), hpk);
                    int p3 = __builtin_amdgcn_ds_bpermute(4 * (8 * c + 3), hpk);
                    int p4 = __builtin_amdgcn_ds_bpermute(4 * (8 * c + 4), hpk);
                    int p5 = __builtin_amdgcn_ds_bpermute(4 * (8 * c + 5), hpk);
                    int p6 = __builtin_amdgcn_ds_bpermute(4 * (8 * c + 6), hpk);
                    int p7 = __builtin_amdgcn_ds_bpermute(4 * (8 * c + 7), hpk);
                    a0_ = fdot2(bcu(va.x),  bcu(p0), a0_);
                    a1_ = fdot2(bcu(va.y),  bcu(p1), a1_);
                    a0_ = fdot2(bcu(va.z),  bcu(p2), a0_);
                    a1_ = fdot2(bcu(va.w),  bcu(p3), a1_);
                    a0_ = fdot2(bcu(va2.x), bcu(p4), a0_);
                    a1_ = fdot2(bcu(va2.y), bcu(p5), a1_);
                    a0_ = fdot2(bcu(va2.z), bcu(p6), a0_);
                    a1_ = fdot2(bcu(va2.w), bcu(p7), a1_);
                    c0_ = fdot2(bcu(vb.x),  bcu(p0), c0_);
                    c1_ = fdot2(bcu(vb.y),  bcu(p1), c1_);
                    c0_ = fdot2(bcu(vb.z),  bcu(p2), c0_);
                    c1_ = fdot2(bcu(vb.w),  bcu(p3), c1_);
                    c0_ = fdot2(bcu(vb2.x), bcu(p4), c0_);
                    c1_ = fdot2(bcu(vb2.y), bcu(p5), c1_);
                    c0_ = fdot2(bcu(vb2.z), bcu(p6), c0_);
                    c1_ = fdot2(bcu(vb2.w), bcu(p7), c1_);
                }
                z1a0 = a0_ + a1_ + b1r0;
                z1a1 = c0_ + c1_ + b1r1;
            }
            // ---- barrier-free chain st2..st8 ----
            float u0 = fast_tanh(z1a0), u1 = fast_tanh(z1a1);
            float S0 = u0, S1 = u1;
            int upk = pack2h(u0, u1);
            float m0, m1;
            // st2
            BDOT(wa, wb, upk, m0, m1);
            u0 = fast_tanh(z1a0 + a2c * (m0 + w1b20));
            u1 = fast_tanh(z1a1 + a2c * (m1 + w1b21));
            S0 += 2.f * u0; S1 += 2.f * u1;
            upk = pack2h(u0, u1);
            // st3
            BDOT(wa, wb, upk, m0, m1);
            u0 = fast_tanh(z1a0 + a2c * (m0 + w1b20));
            u1 = fast_tanh(z1a1 + a2c * (m1 + w1b21));
            S0 += 2.f * u0; S1 += 2.f * u1;
            upk = pack2h(u0, u1);
            // st4 (k4 uses full dts)
            BDOT(wa, wb, upk, m0, m1);
            u0 = fast_tanh(z1a0 + dts * (m0 + w1b20));
            u1 = fast_tanh(z1a1 + dts * (m1 + w1b21));
            S0 += u0; S1 += u1;
            // st5: z1b = z1a + a6*W12*S + dts*w1b2
            int Spk = pack2h(S0, S1);
            BDOT(wa, wb, Spk, m0, m1);
            const float zb0 = z1a0 + a6 * m0 + dts * w1b20;
            const float zb1 = z1a1 + a6 * m1 + dts * w1b21;
            u0 = fast_tanh(zb0); u1 = fast_tanh(zb1);
            float S20 = u0, S21 = u1;
            upk = pack2h(u0, u1);
            // st6
            BDOT(wa, wb, upk, m0, m1);
            u0 = fast_tanh(zb0 + a2c * (m0 + w1b20));
            u1 = fast_tanh(zb1 + a2c * (m1 + w1b21));
            S20 += 2.f * u0; S21 += 2.f * u1;
            upk = pack2h(u0, u1);
            // st7
            BDOT(wa, wb, upk, m0, m1);
            u0 = fast_tanh(zb0 + a2c * (m0 + w1b20));
            u1 = fast_tanh(zb1 + a2c * (m1 + w1b21));
            S20 += 2.f * u0; S21 += 2.f * u1;
            upk = pack2h(u0, u1);
            // st8
            BDOT(wa, wb, upk, m0, m1);
            u0 = fast_tanh(zb0 + dts * (m0 + w1b20));
            u1 = fast_tanh(zb1 + dts * (m1 + w1b21));
            S20 += u0; S21 += u1;
            shSpp[L] = pack2h(S0 + S20, S1 + S21);
        } else if (w >= 2 && w <= 4) {
            // gates part 1: Whh_g · h (huge window, off critical path)
            const int hpk = shHpk[L];
            float g0, g1;
            BDOT(wa, wb, hpk, g0, g1);
            shGA[w - 2][L] = make_float2(g0, g1);
        } else if (w == 1) {
            // issue gx loads (consumed after B_fin; vmcnt not drained by sync_lds)
            const float* gp = gx + ((size_t)seq * NB + b) * NG;
            gxr = *(const float2*)(gp + r0);
            gxz = *(const float2*)(gp + NH + r0);
            gxn = *(const float2*)(gp + 2 * NH + r0);
        }

        sync_lds();  // ===== B2: Spp + GA visible =====

        float hB0 = 0.f, hB1 = 0.f;
        if (w == 1) {
            const int spk = shSpp[L];
            float q0, q1;
            BDOT(wa, wb, spk, q0, q1);
            hB0 = h0 + a6 * q0 + 2.f * dts * b20;
            hB1 = h1 + a6 * q1 + 2.f * dts * b21;
        } else if (w >= 5) {
            const int spk = shSpp[L];
            float s0, s1;
            BDOT(wa, wb, spk, s0, s1);
            shGS[w - 5][L] = make_float2(s0, s1);
        }

        sync_lds();  // ===== B_fin: GS visible =====

        if (w == 1) {
            const float tdts = 2.f * dts;
            float2 GAr = shGA[0][L], GAz = shGA[1][L], GAn = shGA[2][L];
            float2 GSr = shGS[0][L], GSz = shGS[1][L], GSn = shGS[2][L];
            const float ghr0 = GAr.x + a6 * GSr.x + tdts * sbr0 + bhr0;
            const float ghr1 = GAr.y + a6 * GSr.y + tdts * sbr1 + bhr1;
            const float ghz0 = GAz.x + a6 * GSz.x + tdts * sbz0 + bhz0;
            const float ghz1 = GAz.y + a6 * GSz.y + tdts * sbz1 + bhz1;
            const float ghn0 = GAn.x + a6 * GSn.x + tdts * sbn0 + bhn0;
            const float ghn1 = GAn.y + a6 * GSn.y + tdts * sbn1 + bhn1;
            const float rr0 = fast_sig(gxr.x + ghr0);
            const float rr1 = fast_sig(gxr.y + ghr1);
            const float zz0 = fast_sig(gxz.x + ghz0);
            const float zz1 = fast_sig(gxz.y + ghz1);
            const float nn0 = fast_tanh(gxn.x + rr0 * ghn0);
            const float nn1 = fast_tanh(gxn.y + rr1 * ghn1);
            h0 = (1.f - zz0) * nn0 + zz0 * hB0;
            h1 = (1.f - zz1) * nn1 + zz1 * hB1;
            shHpk[L] = pack2h(h0, h1);   // visible at next iteration's B_h
        }
    }

    // ---- epilogue: heads from final fp32 h ----
    if (w == 1) { shHfl[r0] = h0; shHfl[r1] = h1; }
    __syncthreads();
    if (t < 256) {
        const int rr = t >> 1;
        const int pp = t & 1;
        const int sel = rr >> 6;
        const int l = rr & 63;
        const float* Wf = sel ? W_logvar : W_mean;
        const int hc0 = 64 * pp;
        float a0 = 0.f, a1 = 0.f;
#pragma unroll
        for (int jj = 0; jj < 16; jj++) {
            float4 w4 = *(const float4*)&Wf[l * NH + hc0 + 4 * jj];
            float4 h4 = *(const float4*)(shHfl + hc0 + 4 * jj);
            a0 = fmaf(w4.x, h4.x, a0);
            a1 = fmaf(w4.y, h4.y, a1);
            a0 = fmaf(w4.z, h4.z, a0);
            a1 = fmaf(w4.w, h4.w, a1);
        }
        float acc = red1(a0 + a1);
        if (pp == 0) {
            const float bias = sel ? b_logvar[l] : b_mean[l];
            out[sel * (NB * NL) + b * NL + l] = acc + bias;
        }
    }
}

extern "C" void kernel_launch(void* const* d_in, const int* in_sizes, int n_in,
                              void* d_out, int out_size, void* d_ws, size_t ws_size,
                              hipStream_t stream)
{
    const float* x        = (const float*)d_in[0];
    const float* times    = (const float*)d_in[1];
    const float* W_ih     = (const float*)d_in[2];
    const float* W_hh     = (const float*)d_in[3];
    const float* b_ih     = (const float*)d_in[4];
    const float* b_hh     = (const float*)d_in[5];
    const float* W1       = (const float*)d_in[6];
    const float* b1       = (const float*)d_in[7];
    const float* W2       = (const float*)d_in[8];
    const float* b2       = (const float*)d_in[9];
    const float* W_mean   = (const float*)d_in[10];
    const float* b_mean   = (const float*)d_in[11];
    const float* W_logvar = (const float*)d_in[12];
    const float* b_logvar = (const float*)d_in[13];
    float* out = (float*)d_out;

    const size_t need = (size_t)NS * NB * NG * sizeof(float);  // ~50.3 MB
    float* gxbuf;
    if (d_ws != nullptr && ws_size >= need) {
        gxbuf = (float*)d_ws;
    } else {
        void* p = nullptr;
        hipGetSymbolAddress(&p, HIP_SYMBOL(g_gxfb));
        gxbuf = (float*)p;
    }

    gx_kernel<<<NS, 384, 0, stream>>>(x, W_ih, b_ih, gxbuf);
    prep_kernel<<<512, 128, 0, stream>>>(W1, W_hh, W2, b2);
    rnn_kernel<<<NB, 512, 0, stream>>>(times, b_hh, b1, b2,
                                       W_mean, b_mean, W_logvar, b_logvar,
                                       gxbuf, out);
}

// Round 12
// 1301.660 us; speedup vs baseline: 1.0578x; 1.0578x over previous
//
#include <hip/hip_runtime.h>

#define NB 128
#define NS 256
#define NI 64
#define NH 128
#define NL 64
#define NG 384  // 3*NH

typedef _Float16 f16;
typedef __attribute__((ext_vector_type(2))) _Float16 f16x2;

__device__ __forceinline__ float fast_tanh(float x) {
    float e = __expf(2.0f * x);
    return 1.0f - 2.0f / (e + 1.0f);
}
__device__ __forceinline__ float fast_sig(float x) {
    return 1.0f / (1.0f + __expf(-x));
}
__device__ __forceinline__ float red1(float a) {  // epilogue pair-reduce
    int ai = __builtin_bit_cast(int, a);
    int bi = __builtin_amdgcn_update_dpp(0, ai, 0xB1, 0xF, 0xF, true);
    return a + __builtin_bit_cast(float, bi);
}
__device__ __forceinline__ float fdot2(f16x2 a, f16x2 b, float c) {
#if __has_builtin(__builtin_amdgcn_fdot2)
    return __builtin_amdgcn_fdot2(a, b, c, false);
#else
    return c + (float)a.x * (float)b.x + (float)a.y * (float)b.y;
#endif
}
__device__ __forceinline__ f16x2 bcu(unsigned int u) {
    return __builtin_bit_cast(f16x2, u);
}
__device__ __forceinline__ int pack2h(float x, float y) {
    f16x2 v; v.x = (f16)x; v.y = (f16)y;
    return __builtin_bit_cast(int, v);
}
// LDS-only workgroup barrier (no vmcnt drain)
__device__ __forceinline__ void sync_lds() {
    asm volatile("s_waitcnt lgkmcnt(0)" ::: "memory");
    __builtin_amdgcn_s_barrier();
    asm volatile("" ::: "memory");
}
// same-wave LDS visibility fence (write -> read, one wave, no barrier)
__device__ __forceinline__ void fence_lds_wave() {
    asm volatile("s_waitcnt lgkmcnt(0)" ::: "memory");
}

// ---- f16 weight tables (pre-rounded once by prep_kernel) ----
__device__ __align__(16) f16 g_W1h[NH * NH];
__device__ __align__(16) f16 g_W2h[NH * NH];
__device__ __align__(16) f16 g_W12h[NH * NH];
__device__ __align__(16) f16 g_Whhh[3 * NH * NH];
__device__ __align__(16) f16 g_Whh2h[3 * NH * NH];
__device__ float g_w1b2[NH];
__device__ float g_whhb2[3 * NH];
__device__ float g_gxfb[(size_t)NS * NB * NG];  // gx fallback if ws too small

// ---------------------------------------------------------------------------
// GX precompute: gx[s][b][j] = b_ih[j] + sum_c x[b][s][c] * W_ih[j][c]
// ---------------------------------------------------------------------------
__global__ __launch_bounds__(384)
void gx_kernel(const float* __restrict__ x, const float* __restrict__ W_ih,
               const float* __restrict__ b_ih, float* __restrict__ gx)
{
    const int s = blockIdx.x;
    const int j = threadIdx.x;
    __shared__ __align__(16) float xs[NB * NI];
    for (int idx = j; idx < NB * NI; idx += 384) {
        int bb = idx >> 6, cc = idx & 63;
        xs[idx] = x[(bb * NS + s) * NI + cc];
    }
    float w[64];
#pragma unroll
    for (int c = 0; c < 64; c += 4)
        *(float4*)&w[c] = *(const float4*)&W_ih[j * NI + c];
    const float bj = b_ih[j];
    __syncthreads();
    for (int bb = 0; bb < NB; bb++) {
        const float* xr = xs + bb * NI;
        float a0 = 0.f, a1 = 0.f, a2 = 0.f, a3 = 0.f;
#pragma unroll
        for (int c = 0; c < 64; c += 4) {
            a0 = fmaf(w[c + 0], xr[c + 0], a0);
            a1 = fmaf(w[c + 1], xr[c + 1], a1);
            a2 = fmaf(w[c + 2], xr[c + 2], a2);
            a3 = fmaf(w[c + 3], xr[c + 3], a3);
        }
        gx[((size_t)s * NB + bb) * NG + j] = ((a0 + a1) + (a2 + a3)) + bj;
    }
}

// ---------------------------------------------------------------------------
// Setup (fp32 math, then round to f16)
// ---------------------------------------------------------------------------
__global__ __launch_bounds__(128)
void prep_kernel(const float* __restrict__ W1, const float* __restrict__ Whh,
                 const float* __restrict__ W2, const float* __restrict__ b2)
{
    const int i = blockIdx.x;   // 0..511
    const int j = threadIdx.x;  // 0..127
    __shared__ float rowA[NH];
    __shared__ float red[NH];
    const float* src = (i < NH) ? (W1 + i * NH) : (Whh + (size_t)(i - NH) * NH);
    rowA[j] = src[j];
    __syncthreads();
    float acc = 0.f;
    for (int k = 0; k < NH; k++) acc = fmaf(rowA[k], W2[k * NH + j], acc);
    if (i < NH) {
        g_W12h[i * NH + j] = (f16)acc;
        g_W1h[i * NH + j]  = (f16)rowA[j];
        g_W2h[i * NH + j]  = (f16)W2[i * NH + j];
    } else {
        g_Whh2h[(size_t)(i - NH) * NH + j] = (f16)acc;
        g_Whhh[(size_t)(i - NH) * NH + j]  = (f16)rowA[j];
    }
    red[j] = rowA[j] * b2[j];
    __syncthreads();
    for (int off = 64; off > 0; off >>= 1) {
        if (j < off) red[j] += red[j + off];
        __syncthreads();
    }
    if (j == 0) {
        if (i < NH) g_w1b2[i] = red[0];
        else        g_whhb2[i - NH] = red[0];
    }
}

// ---------------------------------------------------------------------------
// Broadcast-read dot: source = 64-u32 pack array in LDS (256B); all lanes
// read the SAME 16B chunk per instruction (same-address broadcast = conflict
// free). Weights: int[64] per row in registers, literal indices only.
// ---------------------------------------------------------------------------
#define BDOTB(WA, WB, SRC, O0, O1)                                             \
    {                                                                          \
        float a0_ = 0.f, a1_ = 0.f, b0_ = 0.f, b1_ = 0.f;                      \
        const uint4* sp_ = (const uint4*)(SRC);                                \
        _Pragma("unroll") for (int j_ = 0; j_ < 16; j_++)                      \
        {                                                                      \
            uint4 v_ = sp_[j_];                                                \
            a0_ = fdot2(bcu(WA[4 * j_ + 0]), bcu(v_.x), a0_);                  \
            a1_ = fdot2(bcu(WA[4 * j_ + 1]), bcu(v_.y), a1_);                  \
            a0_ = fdot2(bcu(WA[4 * j_ + 2]), bcu(v_.z), a0_);                  \
            a1_ = fdot2(bcu(WA[4 * j_ + 3]), bcu(v_.w), a1_);                  \
            b0_ = fdot2(bcu(WB[4 * j_ + 0]), bcu(v_.x), b0_);                  \
            b1_ = fdot2(bcu(WB[4 * j_ + 1]), bcu(v_.y), b1_);                  \
            b0_ = fdot2(bcu(WB[4 * j_ + 2]), bcu(v_.z), b0_);                  \
            b1_ = fdot2(bcu(WB[4 * j_ + 3]), bcu(v_.w), b1_);                  \
        }                                                                      \
        O0 = a0_ + a1_;                                                        \
        O1 = b0_ + b1_;                                                        \
    }

// load one full f16 row (128 = 256B) into int[64]
#define LOADROW(DST, BASE)                                                     \
    {                                                                          \
        const uint4* p_ = (const uint4*)(BASE);                                \
        _Pragma("unroll") for (int j_ = 0; j_ < 16; j_++)                      \
        {                                                                      \
            uint4 v_ = p_[j_];                                                 \
            DST[4 * j_ + 0] = v_.x; DST[4 * j_ + 1] = v_.y;                    \
            DST[4 * j_ + 2] = v_.z; DST[4 * j_ + 3] = v_.w;                    \
        }                                                                      \
    }

#define PIN2(A, B)                                                             \
    _Pragma("unroll") for (int i_ = 0; i_ < 64; i_++)                          \
    { asm volatile("" : "+v"(A[i_]), "+v"(B[i_])); }

// ---------------------------------------------------------------------------
// Main recurrence: 1 WG / batch element, 512 threads = 8 waves (2/SIMD).
// w0: st1 (W1 streamed from swizzled LDS) + barrier-FREE 7-stage chain (W12
//     regs; per-stage same-wave LDS round trip: 1 ds_write + lgkmcnt + 16
//     broadcast ds_read_b128 — no s_barrier).
// w1: W2 regs -> hB; owns fp32 h; GRU.  w4-6: Whh_g·h (chain window).
// w2,w3,w7: Whh2_g·Spp.  3 barriers/step: B_S, B_G, B_h.
// ---------------------------------------------------------------------------
__global__ __launch_bounds__(512, 2)
void rnn_kernel(const float* __restrict__ times, const float* __restrict__ b_hh,
                const float* __restrict__ b1, const float* __restrict__ b2,
                const float* __restrict__ W_mean, const float* __restrict__ b_mean,
                const float* __restrict__ W_logvar, const float* __restrict__ b_logvar,
                const float* __restrict__ gx,
                float* __restrict__ out)
{
    const int b = blockIdx.x;
    const int t = threadIdx.x;   // 0..511
    const int w = t >> 6;        // wave 0..7
    const int L = t & 63;        // lane
    const int r0 = 2 * L, r1 = 2 * L + 1;
    const int key = L & 7;       // sW1 swizzle key ((r>>1)&7 for rows 2L,2L+1)

    __shared__ float shT[NS];
    __shared__ __align__(16) int shHpk[64];   // h pack
    __shared__ __align__(16) int shUc[64];    // chain round-trip pack
    __shared__ __align__(16) int shSpp[64];   // (S+S2) pack
    __shared__ float2 shGA[3][64];            // Whh_g · h
    __shared__ float2 shGS[3][64];            // Whh2_g · Spp
    __shared__ __align__(16) uint4 sW1c[NH * 16];  // 32KB swizzled W1
    __shared__ __align__(16) float shHfl[NH];

    // stage swizzled W1: chunk j of row r stored at (r<<4) | (j ^ ((r>>1)&7))
    for (int idx = t; idx < NH * 16; idx += 512) {
        const int r = idx >> 4, j = idx & 15;
        sW1c[(r << 4) | (j ^ ((r >> 1) & 7))] = ((const uint4*)g_W1h)[idx];
    }
    for (int i = t; i < NS; i += 512) shT[i] = times[i];
    if (t < 64) shHpk[t] = 0;
    __syncthreads();

    // ---- per-wave persistent weight rows (pinned to arch VGPRs) ----
    int wa[64], wb[64];
    if (w == 0) {
        LOADROW(wa, g_W12h + r0 * NH);
        LOADROW(wb, g_W12h + r1 * NH);
    } else if (w == 1) {
        LOADROW(wa, g_W2h + r0 * NH);
        LOADROW(wb, g_W2h + r1 * NH);
    } else if (w >= 4 && w <= 6) {
        const int g = w - 4;
        LOADROW(wa, g_Whhh + (size_t)(g * NH + r0) * NH);
        LOADROW(wb, g_Whhh + (size_t)(g * NH + r1) * NH);
    } else {  // w == 2,3,7 -> Whh2 gates 0,1,2
        const int g = (w == 2) ? 0 : (w == 3) ? 1 : 2;
        LOADROW(wa, g_Whh2h + (size_t)(g * NH + r0) * NH);
        LOADROW(wb, g_Whh2h + (size_t)(g * NH + r1) * NH);
    }

    const float b1r0 = b1[r0], b1r1 = b1[r1];
    const float w1b20 = g_w1b2[r0], w1b21 = g_w1b2[r1];
    const float b20 = b2[r0], b21 = b2[r1];
    float bhr0 = 0, bhr1 = 0, bhz0 = 0, bhz1 = 0, bhn0 = 0, bhn1 = 0;
    float sbr0 = 0, sbr1 = 0, sbz0 = 0, sbz1 = 0, sbn0 = 0, sbn1 = 0;
    if (w == 1) {
        bhr0 = b_hh[r0]; bhr1 = b_hh[r1];
        bhz0 = b_hh[NH + r0]; bhz1 = b_hh[NH + r1];
        bhn0 = b_hh[2 * NH + r0]; bhn1 = b_hh[2 * NH + r1];
        sbr0 = g_whhb2[r0]; sbr1 = g_whhb2[r1];
        sbz0 = g_whhb2[NH + r0]; sbz1 = g_whhb2[NH + r1];
        sbn0 = g_whhb2[2 * NH + r0]; sbn1 = g_whhb2[2 * NH + r1];
    }

    float h0 = 0.f, h1 = 0.f;           // live in w1
    float2 gxr, gxz, gxn;               // w1 gx prefetch

    for (int si = 0; si < NS; ++si) {
        const int seq = NS - 1 - si;
        const float dt = (si == 0) ? 0.f : (shT[seq] - shT[seq + 1]);
        const float dts = 0.5f * dt;   // substep dt (N_SUB=2)
        const float a2c = 0.5f * dts;
        const float a6 = dts * (1.f / 6.f);

        // ===== Phase A (after B_h): chain on w0; Whh·h on w4-6 =====
        if (w == 0) {
            PIN2(wa, wb);
            // st1: z1a = W1 h + b1  (W1 from swizzled LDS, h broadcast)
            float z0, z1;
            {
                float a0_ = 0.f, a1_ = 0.f, c0_ = 0.f, c1_ = 0.f;
#pragma unroll
                for (int j = 0; j < 16; j++) {
                    uint4 hv = ((const uint4*)shHpk)[j];
                    uint4 va = sW1c[(r0 << 4) | (j ^ key)];
                    uint4 vb = sW1c[(r1 << 4) | (j ^ key)];
                    a0_ = fdot2(bcu(va.x), bcu(hv.x), a0_);
                    a1_ = fdot2(bcu(va.y), bcu(hv.y), a1_);
                    a0_ = fdot2(bcu(va.z), bcu(hv.z), a0_);
                    a1_ = fdot2(bcu(va.w), bcu(hv.w), a1_);
                    c0_ = fdot2(bcu(vb.x), bcu(hv.x), c0_);
                    c1_ = fdot2(bcu(vb.y), bcu(hv.y), c1_);
                    c0_ = fdot2(bcu(vb.z), bcu(hv.z), c0_);
                    c1_ = fdot2(bcu(vb.w), bcu(hv.w), c1_);
                }
                z0 = a0_ + a1_ + b1r0;
                z1 = c0_ + c1_ + b1r1;
            }
            float u0 = fast_tanh(z0), u1 = fast_tanh(z1);
            float S0 = u0, S1 = u1;
            int upk = pack2h(u0, u1);
            float m0, m1;

            // ---- barrier-free chain: same-wave LDS round trips ----
#define CSTAGE(ZB0, ZB1, COEF)                                                 \
            shUc[L] = upk;                                                     \
            fence_lds_wave();                                                  \
            BDOTB(wa, wb, shUc, m0, m1);                                       \
            u0 = fast_tanh((ZB0) + (COEF) * (m0 + w1b20));                     \
            u1 = fast_tanh((ZB1) + (COEF) * (m1 + w1b21));

            // st2, st3 (coef a2c), st4 (coef dts)
            CSTAGE(z0, z1, a2c); S0 += 2.f * u0; S1 += 2.f * u1; upk = pack2h(u0, u1);
            CSTAGE(z0, z1, a2c); S0 += 2.f * u0; S1 += 2.f * u1; upk = pack2h(u0, u1);
            CSTAGE(z0, z1, dts); S0 += u0; S1 += u1;
            // st5: z1b = z1a + a6*W12*S + dts*w1b2
            upk = pack2h(S0, S1);
            shUc[L] = upk;
            fence_lds_wave();
            BDOTB(wa, wb, shUc, m0, m1);
            const float zb0 = z0 + a6 * m0 + dts * w1b20;
            const float zb1 = z1 + a6 * m1 + dts * w1b21;
            u0 = fast_tanh(zb0); u1 = fast_tanh(zb1);
            float S20 = u0, S21 = u1;
            upk = pack2h(u0, u1);
            // st6, st7 (coef a2c), st8 (coef dts)
            CSTAGE(zb0, zb1, a2c); S20 += 2.f * u0; S21 += 2.f * u1; upk = pack2h(u0, u1);
            CSTAGE(zb0, zb1, a2c); S20 += 2.f * u0; S21 += 2.f * u1; upk = pack2h(u0, u1);
            CSTAGE(zb0, zb1, dts); S20 += u0; S21 += u1;
#undef CSTAGE
            shSpp[L] = pack2h(S0 + S20, S1 + S21);
        } else if (w >= 4 && w <= 6) {
            PIN2(wa, wb);
            float g0, g1;
            BDOTB(wa, wb, shHpk, g0, g1);
            shGA[w - 4][L] = make_float2(g0, g1);
        } else if (w == 1) {
            // issue gx loads early; consumed in phase C (vmcnt not drained)
            const float* gp = gx + ((size_t)seq * NB + b) * NG;
            gxr = *(const float2*)(gp + r0);
            gxz = *(const float2*)(gp + NH + r0);
            gxn = *(const float2*)(gp + 2 * NH + r0);
        }

        sync_lds();  // ===== B_S: Spp (+GA) visible =====

        float hB0 = 0.f, hB1 = 0.f;
        if (w == 1) {
            PIN2(wa, wb);
            float q0, q1;
            BDOTB(wa, wb, shSpp, q0, q1);
            hB0 = h0 + a6 * q0 + 2.f * dts * b20;
            hB1 = h1 + a6 * q1 + 2.f * dts * b21;
        } else if (w == 2 || w == 3 || w == 7) {
            PIN2(wa, wb);
            const int g = (w == 2) ? 0 : (w == 3) ? 1 : 2;
            float s0, s1;
            BDOTB(wa, wb, shSpp, s0, s1);
            shGS[g][L] = make_float2(s0, s1);
        }

        sync_lds();  // ===== B_G: GS visible =====

        if (w == 1) {
            const float tdts = 2.f * dts;
            float2 GAr = shGA[0][L], GAz = shGA[1][L], GAn = shGA[2][L];
            float2 GSr = shGS[0][L], GSz = shGS[1][L], GSn = shGS[2][L];
            const float ghr0 = GAr.x + a6 * GSr.x + tdts * sbr0 + bhr0;
            const float ghr1 = GAr.y + a6 * GSr.y + tdts * sbr1 + bhr1;
            const float ghz0 = GAz.x + a6 * GSz.x + tdts * sbz0 + bhz0;
            const float ghz1 = GAz.y + a6 * GSz.y + tdts * sbz1 + bhz1;
            const float ghn0 = GAn.x + a6 * GSn.x + tdts * sbn0 + bhn0;
            const float ghn1 = GAn.y + a6 * GSn.y + tdts * sbn1 + bhn1;
            const float rr0 = fast_sig(gxr.x + ghr0);
            const float rr1 = fast_sig(gxr.y + ghr1);
            const float zz0 = fast_sig(gxz.x + ghz0);
            const float zz1 = fast_sig(gxz.y + ghz1);
            const float nn0 = fast_tanh(gxn.x + rr0 * ghn0);
            const float nn1 = fast_tanh(gxn.y + rr1 * ghn1);
            h0 = (1.f - zz0) * nn0 + zz0 * hB0;
            h1 = (1.f - zz1) * nn1 + zz1 * hB1;
            shHpk[L] = pack2h(h0, h1);
        }

        sync_lds();  // ===== B_h: h' visible =====
    }

    // ---- epilogue: heads from final fp32 h ----
    if (w == 1) { shHfl[r0] = h0; shHfl[r1] = h1; }
    __syncthreads();
    if (t < 256) {
        const int rr = t >> 1;
        const int pp = t & 1;
        const int sel = rr >> 6;
        const int l = rr & 63;
        const float* Wf = sel ? W_logvar : W_mean;
        const int hc0 = 64 * pp;
        float a0 = 0.f, a1 = 0.f;
#pragma unroll
        for (int jj = 0; jj < 16; jj++) {
            float4 w4 = *(const float4*)&Wf[l * NH + hc0 + 4 * jj];
            float4 h4 = *(const float4*)(shHfl + hc0 + 4 * jj);
            a0 = fmaf(w4.x, h4.x, a0);
            a1 = fmaf(w4.y, h4.y, a1);
            a0 = fmaf(w4.z, h4.z, a0);
            a1 = fmaf(w4.w, h4.w, a1);
        }
        float acc = red1(a0 + a1);
        if (pp == 0) {
            const float bias = sel ? b_logvar[l] : b_mean[l];
            out[sel * (NB * NL) + b * NL + l] = acc + bias;
        }
    }
}

extern "C" void kernel_launch(void* const* d_in, const int* in_sizes, int n_in,
                              void* d_out, int out_size, void* d_ws, size_t ws_size,
                              hipStream_t stream)
{
    const float* x        = (const float*)d_in[0];
    const float* times    = (const float*)d_in[1];
    const float* W_ih     = (const float*)d_in[2];
    const float* W_hh     = (const float*)d_in[3];
    const float* b_ih     = (const float*)d_in[4];
    const float* b_hh     = (const float*)d_in[5];
    const float* W1       = (const float*)d_in[6];
    const float* b1       = (const float*)d_in[7];
    const float* W2       = (const float*)d_in[8];
    const float* b2       = (const float*)d_in[9];
    const float* W_mean   = (const float*)d_in[10];
    const float* b_mean   = (const float*)d_in[11];
    const float* W_logvar = (const float*)d_in[12];
    const float* b_logvar = (const float*)d_in[13];
    float* out = (float*)d_out;

    const size_t need = (size_t)NS * NB * NG * sizeof(float);  // ~50.3 MB
    float* gxbuf;
    if (d_ws != nullptr && ws_size >= need) {
        gxbuf = (float*)d_ws;
    } else {
        void* p = nullptr;
        hipGetSymbolAddress(&p, HIP_SYMBOL(g_gxfb));
        gxbuf = (float*)p;
    }

    gx_kernel<<<NS, 384, 0, stream>>>(x, W_ih, b_ih, gxbuf);
    prep_kernel<<<512, 128, 0, stream>>>(W1, W_hh, W2, b2);
    rnn_kernel<<<NB, 512, 0, stream>>>(times, b_hh, b1, b2,
                                       W_mean, b_mean, W_logvar, b_logvar,
                                       gxbuf, out);
}

// Round 13
// 912.219 us; speedup vs baseline: 1.5094x; 1.4269x over previous
//
#include <hip/hip_runtime.h>

#define NB 128
#define NS 256
#define NI 64
#define NH 128
#define NL 64
#define NG 384  // 3*NH

typedef _Float16 f16;
typedef __attribute__((ext_vector_type(2))) _Float16 f16x2;

__device__ __forceinline__ float fast_tanh(float x) {
    float e = __expf(2.0f * x);
    return 1.0f - 2.0f / (e + 1.0f);
}
__device__ __forceinline__ float fast_sig(float x) {
    return 1.0f / (1.0f + __expf(-x));
}
// quad reduce via DPP (pure VALU, no LDS pipe)
template <int CTRL>
__device__ __forceinline__ float dpp_xor_add(float a) {
    int ai = __builtin_bit_cast(int, a);
    int bi = __builtin_amdgcn_update_dpp(0, ai, CTRL, 0xF, 0xF, true);
    return a + __builtin_bit_cast(float, bi);
}
__device__ __forceinline__ float quad_red(float a) {
    a = dpp_xor_add<0xB1>(a);  // quad_perm [1,0,3,2]  (xor 1)
    a = dpp_xor_add<0x4E>(a);  // quad_perm [2,3,0,1]  (xor 2)
    return a;
}
__device__ __forceinline__ float fdot2(f16x2 a, f16x2 b, float c) {
#if __has_builtin(__builtin_amdgcn_fdot2)
    return __builtin_amdgcn_fdot2(a, b, c, false);
#else
    return c + (float)a.x * (float)b.x + (float)a.y * (float)b.y;
#endif
}
__device__ __forceinline__ f16x2 bc16(unsigned int u) {
    return __builtin_bit_cast(f16x2, u);
}
// LDS-only workgroup barrier: does NOT drain vmcnt (global prefetch stays
// in flight). Write->sync->read pattern: lgkmcnt(0) commits my ds_write,
// s_barrier orders across waves, memory clobbers pin LDS ops.
__device__ __forceinline__ void sync_lds() {
    asm volatile("s_waitcnt lgkmcnt(0)" ::: "memory");
    __builtin_amdgcn_s_barrier();
    asm volatile("" ::: "memory");
}

// ---- f16 weight tables (pre-rounded once by prep_kernel) ----
__device__ __align__(16) f16 g_W1h[NH * NH];
__device__ __align__(16) f16 g_W2h[NH * NH];
__device__ __align__(16) f16 g_W12h[NH * NH];
__device__ __align__(16) f16 g_Whhh[3 * NH * NH];
__device__ __align__(16) f16 g_Whh2h[3 * NH * NH];
__device__ float g_w1b2[NH];
__device__ float g_whhb2[3 * NH];

// ---------------------------------------------------------------------------
// GX precompute: gx[s][b][j] = b_ih[j] + sum_c x[b][s][c] * W_ih[j][c]
// ---------------------------------------------------------------------------
__global__ __launch_bounds__(384)
void gx_kernel(const float* __restrict__ x, const float* __restrict__ W_ih,
               const float* __restrict__ b_ih, float* __restrict__ gx)
{
    const int s = blockIdx.x;
    const int j = threadIdx.x;
    __shared__ __align__(16) float xs[NB * NI];
    for (int idx = j; idx < NB * NI; idx += 384) {
        int bb = idx >> 6, cc = idx & 63;
        xs[idx] = x[(bb * NS + s) * NI + cc];
    }
    float w[64];
#pragma unroll
    for (int c = 0; c < 64; c += 4)
        *(float4*)&w[c] = *(const float4*)&W_ih[j * NI + c];
    const float bj = b_ih[j];
    __syncthreads();
    for (int bb = 0; bb < NB; bb++) {
        const float* xr = xs + bb * NI;
        float a0 = 0.f, a1 = 0.f, a2 = 0.f, a3 = 0.f;
#pragma unroll
        for (int c = 0; c < 64; c += 4) {
            a0 = fmaf(w[c + 0], xr[c + 0], a0);
            a1 = fmaf(w[c + 1], xr[c + 1], a1);
            a2 = fmaf(w[c + 2], xr[c + 2], a2);
            a3 = fmaf(w[c + 3], xr[c + 3], a3);
        }
        gx[((size_t)s * NB + bb) * NG + j] = ((a0 + a1) + (a2 + a3)) + bj;
    }
}

// ---------------------------------------------------------------------------
// Setup (fp32 math, then round to f16): W12=W1@W2, Whh2=Whh@W2, W1b2, Whhb2,
// plus f16 copies of W1, W2, Whh.
// ---------------------------------------------------------------------------
__global__ __launch_bounds__(128)
void prep_kernel(const float* __restrict__ W1, const float* __restrict__ Whh,
                 const float* __restrict__ W2, const float* __restrict__ b2)
{
    const int i = blockIdx.x;   // 0..511
    const int j = threadIdx.x;  // 0..127
    __shared__ float rowA[NH];
    __shared__ float red[NH];
    const float* src = (i < NH) ? (W1 + i * NH) : (Whh + (size_t)(i - NH) * NH);
    rowA[j] = src[j];
    __syncthreads();
    float acc = 0.f;
    for (int k = 0; k < NH; k++) acc = fmaf(rowA[k], W2[k * NH + j], acc);
    if (i < NH) {
        g_W12h[i * NH + j] = (f16)acc;
        g_W1h[i * NH + j]  = (f16)rowA[j];
        g_W2h[i * NH + j]  = (f16)W2[i * NH + j];
    } else {
        g_Whh2h[(size_t)(i - NH) * NH + j] = (f16)acc;
        g_Whhh[(size_t)(i - NH) * NH + j]  = (f16)rowA[j];
    }
    red[j] = rowA[j] * b2[j];
    __syncthreads();
    for (int off = 64; off > 0; off >>= 1) {
        if (j < off) red[j] += red[j + off];
        __syncthreads();
    }
    if (j == 0) {
        if (i < NH) g_w1b2[i] = red[0];
        else        g_whhb2[i - NH] = red[0];
    }
}

// ---------------------------------------------------------------------------
// dot helpers: 512 threads, 4 lanes per row. Quad lane p owns cols
// [32p, 32p+32) as 4 rotated 16B chunks (disjoint bank groups per quad).
// Weights: f16x2[16] per matrix in registers, literal indices only.
// ---------------------------------------------------------------------------
#define CHNK(SRC, OB) (*(const uint4*)((const unsigned char*)(SRC) + (OB)))

// 4 independent accumulator chains per weight (depth 1 per chunk)
#define D4(W, K, V, A0, A1, A2, A3)                                            \
    A0 = fdot2(W[K + 0], bc16((V).x), A0);                                     \
    A1 = fdot2(W[K + 1], bc16((V).y), A1);                                     \
    A2 = fdot2(W[K + 2], bc16((V).z), A2);                                     \
    A3 = fdot2(W[K + 3], bc16((V).w), A3);

// 2 chains per weight (for the 4-weight dot)
#define D2(W, K, V, A0, A1)                                                    \
    A0 = fdot2(W[K + 0], bc16((V).x), A0);                                     \
    A1 = fdot2(W[K + 1], bc16((V).y), A1);                                     \
    A0 = fdot2(W[K + 2], bc16((V).z), A0);                                     \
    A1 = fdot2(W[K + 3], bc16((V).w), A1);

#define DOT1(W, SRC, OUT)                                                      \
    {                                                                          \
        float a0_ = 0.f, a1_ = 0.f, a2_ = 0.f, a3_ = 0.f;                      \
        { uint4 v_ = CHNK(SRC, ob0); D4(W, 0,  v_, a0_, a1_, a2_, a3_) }       \
        { uint4 v_ = CHNK(SRC, ob1); D4(W, 4,  v_, a0_, a1_, a2_, a3_) }       \
        { uint4 v_ = CHNK(SRC, ob2); D4(W, 8,  v_, a0_, a1_, a2_, a3_) }       \
        { uint4 v_ = CHNK(SRC, ob3); D4(W, 12, v_, a0_, a1_, a2_, a3_) }       \
        OUT = quad_red((a0_ + a1_) + (a2_ + a3_));                             \
    }

#define DOT2S(WA, WB, SRC, OA, OB)                                             \
    {                                                                          \
        float a0_ = 0.f, a1_ = 0.f, a2_ = 0.f, a3_ = 0.f;                      \
        float b0_ = 0.f, b1_ = 0.f, b2_ = 0.f, b3_ = 0.f;                      \
        { uint4 v_ = CHNK(SRC, ob0); D4(WA, 0,  v_, a0_, a1_, a2_, a3_) D4(WB, 0,  v_, b0_, b1_, b2_, b3_) } \
        { uint4 v_ = CHNK(SRC, ob1); D4(WA, 4,  v_, a0_, a1_, a2_, a3_) D4(WB, 4,  v_, b0_, b1_, b2_, b3_) } \
        { uint4 v_ = CHNK(SRC, ob2); D4(WA, 8,  v_, a0_, a1_, a2_, a3_) D4(WB, 8,  v_, b0_, b1_, b2_, b3_) } \
        { uint4 v_ = CHNK(SRC, ob3); D4(WA, 12, v_, a0_, a1_, a2_, a3_) D4(WB, 12, v_, b0_, b1_, b2_, b3_) } \
        OA = quad_red((a0_ + a1_) + (a2_ + a3_));                              \
        OB = quad_red((b0_ + b1_) + (b2_ + b3_));                              \
    }

#define DOT2D(WA, SA, WB, SB, OA, OB)                                          \
    {                                                                          \
        float a0_ = 0.f, a1_ = 0.f, a2_ = 0.f, a3_ = 0.f;                      \
        float b0_ = 0.f, b1_ = 0.f, b2_ = 0.f, b3_ = 0.f;                      \
        { uint4 v_ = CHNK(SA, ob0); uint4 u_ = CHNK(SB, ob0); D4(WA, 0,  v_, a0_, a1_, a2_, a3_) D4(WB, 0,  u_, b0_, b1_, b2_, b3_) } \
        { uint4 v_ = CHNK(SA, ob1); uint4 u_ = CHNK(SB, ob1); D4(WA, 4,  v_, a0_, a1_, a2_, a3_) D4(WB, 4,  u_, b0_, b1_, b2_, b3_) } \
        { uint4 v_ = CHNK(SA, ob2); uint4 u_ = CHNK(SB, ob2); D4(WA, 8,  v_, a0_, a1_, a2_, a3_) D4(WB, 8,  u_, b0_, b1_, b2_, b3_) } \
        { uint4 v_ = CHNK(SA, ob3); uint4 u_ = CHNK(SB, ob3); D4(WA, 12, v_, a0_, a1_, a2_, a3_) D4(WB, 12, u_, b0_, b1_, b2_, b3_) } \
        OA = quad_red((a0_ + a1_) + (a2_ + a3_));                              \
        OB = quad_red((b0_ + b1_) + (b2_ + b3_));                              \
    }

#define DOT4S(WA, WB, WC, WD, SRC, OA, OB, OC, OD)                             \
    {                                                                          \
        float a0_ = 0.f, a1_ = 0.f, b0_ = 0.f, b1_ = 0.f;                      \
        float c0_ = 0.f, c1_ = 0.f, d0_ = 0.f, d1_ = 0.f;                      \
        { uint4 v_ = CHNK(SRC, ob0); D2(WA, 0,  v_, a0_, a1_) D2(WB, 0,  v_, b0_, b1_) D2(WC, 0,  v_, c0_, c1_) D2(WD, 0,  v_, d0_, d1_) } \
        { uint4 v_ = CHNK(SRC, ob1); D2(WA, 4,  v_, a0_, a1_) D2(WB, 4,  v_, b0_, b1_) D2(WC, 4,  v_, c0_, c1_) D2(WD, 4,  v_, d0_, d1_) } \
        { uint4 v_ = CHNK(SRC, ob2); D2(WA, 8,  v_, a0_, a1_) D2(WB, 8,  v_, b0_, b1_) D2(WC, 8,  v_, c0_, c1_) D2(WD, 8,  v_, d0_, d1_) } \
        { uint4 v_ = CHNK(SRC, ob3); D2(WA, 12, v_, a0_, a1_) D2(WB, 12, v_, b0_, b1_) D2(WC, 12, v_, c0_, c1_) D2(WD, 12, v_, d0_, d1_) } \
        OA = quad_red(a0_ + a1_);                                              \
        OB = quad_red(b0_ + b1_);                                              \
        OC = quad_red(c0_ + c1_);                                              \
        OD = quad_red(d0_ + d1_);                                              \
    }

#define LDCH(DST, K, BP, OB)                                                   \
    {                                                                          \
        uint4 v_ = *(const uint4*)((BP) + (OB));                               \
        DST[K + 0] = bc16(v_.x); DST[K + 1] = bc16(v_.y);                      \
        DST[K + 2] = bc16(v_.z); DST[K + 3] = bc16(v_.w);                      \
    }

#define LOADW(DST, BASE)                                                       \
    {                                                                          \
        const unsigned char* bp_ = (const unsigned char*)(BASE);               \
        LDCH(DST, 0, bp_, ob0) LDCH(DST, 4, bp_, ob1)                          \
        LDCH(DST, 8, bp_, ob2) LDCH(DST, 12, bp_, ob3)                         \
    }

// ---------------------------------------------------------------------------
// Main recurrence: 1 WG / batch element, 512 threads (4 lanes per row),
// 8 waves (2/SIMD), 9 serial stages / step. Weights 9 x 16 f16x2 = 144 VGPR.
// ---------------------------------------------------------------------------
__global__ __launch_bounds__(512, 2)
void rnn_kernel(const float* __restrict__ times, const float* __restrict__ b_hh,
                const float* __restrict__ b1, const float* __restrict__ b2,
                const float* __restrict__ W_mean, const float* __restrict__ b_mean,
                const float* __restrict__ W_logvar, const float* __restrict__ b_logvar,
                const float* __restrict__ gx,
                const float* __restrict__ x, const float* __restrict__ W_ih,
                const float* __restrict__ b_ih,
                const int use_gx,
                float* __restrict__ out)
{
    const int b = blockIdx.x;
    const int t = threadIdx.x;    // 0..511
    const int r = t >> 2;         // row 0..127
    const int p = t & 3;          // quad lane

    __shared__ __align__(16) f16 shHh[NH], shUh[NH], shAh[NH];
    __shared__ float shT[NS];
    __shared__ __align__(16) float shGX[NG], shX[NI], shHf[NH];

    // rotated chunk byte offsets: quad lane p owns bytes [64p, 64p+64) of the
    // 256B row; chunk order rotated by p so quads hit disjoint bank groups.
    const int ob0 = 64 * p + 16 * ((0 + p) & 3);
    const int ob1 = 64 * p + 16 * ((1 + p) & 3);
    const int ob2 = 64 * p + 16 * ((2 + p) & 3);
    const int ob3 = 64 * p + 16 * ((3 + p) & 3);

    // ---- register-resident packed-f16 weights (literal indices only) ----
    f16x2 w1p[16], w2p[16], w12p[16];
    f16x2 wh0p[16], wh1p[16], wh2p[16];
    f16x2 ws0p[16], ws1p[16], ws2p[16];
    LOADW(w1p,  g_W1h  + r * NH);
    LOADW(w2p,  g_W2h  + r * NH);
    LOADW(w12p, g_W12h + r * NH);
    LOADW(wh0p, g_Whhh + (0 * NH + r) * NH);
    LOADW(wh1p, g_Whhh + (1 * NH + r) * NH);
    LOADW(wh2p, g_Whhh + (2 * NH + r) * NH);
    LOADW(ws0p, g_Whh2h + (size_t)(0 * NH + r) * NH);
    LOADW(ws1p, g_Whh2h + (size_t)(1 * NH + r) * NH);
    LOADW(ws2p, g_Whh2h + (size_t)(2 * NH + r) * NH);

    const float b1r = b1[r], b2r = b2[r];
    const float bh0 = b_hh[r], bh1 = b_hh[NH + r], bh2 = b_hh[2 * NH + r];
    const float w1b2r = g_w1b2[r];
    const float wb0 = g_whhb2[r], wb1 = g_whhb2[NH + r], wb2 = g_whhb2[2 * NH + r];

    if (t < NS) shT[t] = times[t];
    if (t < NH) shHh[t] = (f16)0.f;
    float h = 0.f;  // fp32 h carried in registers (identical across the quad)
    __syncthreads();

    // gx double-buffer: step si's values loaded one iteration ahead.
    float gxr = 0.f, gxz = 0.f, gxn = 0.f;
    if (use_gx) {
        const float* g = gx + ((size_t)(NS - 1) * NB + b) * NG;
        gxr = g[r]; gxz = g[NH + r]; gxn = g[2 * NH + r];
    }

    for (int si = 0; si < NS; ++si) {
        const int seq = NS - 1 - si;
        const float dt = (si == 0) ? 0.f : (shT[seq] - shT[seq + 1]);
        const float dts = 0.5f * dt;  // substep dt (N_SUB=2)
        const float a2 = 0.5f * dts;
        const float a6 = dts * (1.f / 6.f);

        // issue NEXT step's gx loads now (vmcnt NOT drained by sync_lds, so
        // these stay in flight under the whole step's 9 stages).
        float gnr = 0.f, gnz = 0.f, gnn = 0.f;
        if (use_gx) {
            const int seqn = (seq > 0) ? (seq - 1) : 0;
            const float* g = gx + ((size_t)seqn * NB + b) * NG;
            gnr = g[r]; gnz = g[NH + r]; gnn = g[2 * NH + r];
        } else {
            if (t < NI) shX[t] = x[(b * NS + seq) * NI + t];
            __syncthreads();
            if (t < NG) {
                const float* wr = W_ih + t * NI;
                float a = 0.f;
#pragma unroll
                for (int cc = 0; cc < NI; cc += 4) {
                    float4 w4 = *(const float4*)(wr + cc);
                    a = fmaf(w4.x, shX[cc + 0], a);
                    a = fmaf(w4.y, shX[cc + 1], a);
                    a = fmaf(w4.z, shX[cc + 2], a);
                    a = fmaf(w4.w, shX[cc + 3], a);
                }
                shGX[t] = a + b_ih[t];
            }
            __syncthreads();
        }

        // ======== substep A ========
        float z1a, u, S, m;
        // stage 1: z1 = W1 h + b1
        DOT1(w1p, shHh, z1a);
        z1a += b1r;
        u = fast_tanh(z1a);
        S = u;
        if (p == 0) shUh[r] = (f16)u;
        sync_lds();
        // stage 2
        DOT1(w12p, shUh, m);
        u = fast_tanh(z1a + a2 * (m + w1b2r));
        S += 2.f * u;
        if (p == 0) shUh[r] = (f16)u;
        sync_lds();
        // stage 3
        DOT1(w12p, shUh, m);
        u = fast_tanh(z1a + a2 * (m + w1b2r));
        S += 2.f * u;
        if (p == 0) shUh[r] = (f16)u;
        sync_lds();
        // stage 4 (k4 uses full dts)
        DOT1(w12p, shUh, m);
        u = fast_tanh(z1a + dts * (m + w1b2r));
        S += u;
        if (p == 0) shUh[r] = (f16)S;  // S becomes the stage-5 source
        sync_lds();
        // stage 5: hA = h + a6 W2 S + dts b2 ; z1b = z1a + a6 W12 S + dts W1b2
        float mA, mB;
        DOT2S(w2p, w12p, shUh, mA, mB);
        const float hA = h + a6 * mA + dts * b2r;
        const float z1b = z1a + a6 * mB + dts * w1b2r;
        u = fast_tanh(z1b);
        float S2 = u;
        if (p == 0) { shAh[r] = (f16)hA; shUh[r] = (f16)u; }
        sync_lds();

        // ======== substep B (+ Whh·hA folded in as pair-matvecs) ========
        float g0, g1, g2;
        // stage 6
        DOT2D(w12p, shUh, wh0p, shAh, m, g0);
        u = fast_tanh(z1b + a2 * (m + w1b2r));
        S2 += 2.f * u;
        if (p == 0) shUh[r] = (f16)u;
        sync_lds();
        // stage 7
        DOT2D(w12p, shUh, wh1p, shAh, m, g1);
        u = fast_tanh(z1b + a2 * (m + w1b2r));
        S2 += 2.f * u;
        if (p == 0) shUh[r] = (f16)u;
        sync_lds();
        // stage 8
        DOT2D(w12p, shUh, wh2p, shAh, m, g2);
        u = fast_tanh(z1b + dts * (m + w1b2r));
        S2 += u;
        if (p == 0) shUh[r] = (f16)S2;  // S2 becomes the stage-9 source
        sync_lds();
        // stage 9: 4-matvec over S2 ; GRU (computed on all lanes)
        float n0, n1, n2, n3;
        DOT4S(w2p, ws0p, ws1p, ws2p, shUh, n0, n1, n2, n3);
        const float hB = hA + a6 * n0 + dts * b2r;
        const float rh = g0 + a6 * n1 + dts * wb0 + bh0;
        const float zh = g1 + a6 * n2 + dts * wb1 + bh1;
        const float nh = g2 + a6 * n3 + dts * wb2 + bh2;
        float rx, zx, nx;
        if (use_gx) { rx = gxr; zx = gxz; nx = gxn; }
        else        { rx = shGX[r]; zx = shGX[NH + r]; nx = shGX[2 * NH + r]; }
        const float rr = fast_sig(rx + rh);
        const float zz = fast_sig(zx + zh);
        const float nn = fast_tanh(nx + rr * nh);
        h = (1.f - zz) * nn + zz * hB;
        if (p == 0) shHh[r] = (f16)h;
        // rotate gx double-buffer
        gxr = gnr; gxz = gnz; gxn = gnn;
        sync_lds();
    }

    // ---- epilogue: full-precision heads from fp32 h ----
    if (p == 0) shHf[r] = h;
    __syncthreads();
    const int sel = r >> 6;
    const int l = r & 63;
    const float* Wf = sel ? W_logvar : W_mean;
    const int c0 = 32 * p;
    float a0 = 0.f, a1 = 0.f;
#pragma unroll
    for (int jj = 0; jj < 8; jj++) {
        float4 w4 = *(const float4*)&Wf[l * NH + c0 + 4 * jj];
        float4 h4 = *(const float4*)(shHf + c0 + 4 * jj);
        a0 = fmaf(w4.x, h4.x, a0);
        a1 = fmaf(w4.y, h4.y, a1);
        a0 = fmaf(w4.z, h4.z, a0);
        a1 = fmaf(w4.w, h4.w, a1);
    }
    float acc = quad_red(a0 + a1);
    if (p == 0) {
        const float bias = sel ? b_logvar[l] : b_mean[l];
        out[sel * (NB * NL) + b * NL + l] = acc + bias;
    }
}

extern "C" void kernel_launch(void* const* d_in, const int* in_sizes, int n_in,
                              void* d_out, int out_size, void* d_ws, size_t ws_size,
                              hipStream_t stream)
{
    const float* x        = (const float*)d_in[0];
    const float* times    = (const float*)d_in[1];
    const float* W_ih     = (const float*)d_in[2];
    const float* W_hh     = (const float*)d_in[3];
    const float* b_ih     = (const float*)d_in[4];
    const float* b_hh     = (const float*)d_in[5];
    const float* W1       = (const float*)d_in[6];
    const float* b1       = (const float*)d_in[7];
    const float* W2       = (const float*)d_in[8];
    const float* b2       = (const float*)d_in[9];
    const float* W_mean   = (const float*)d_in[10];
    const float* b_mean   = (const float*)d_in[11];
    const float* W_logvar = (const float*)d_in[12];
    const float* b_logvar = (const float*)d_in[13];
    float* out = (float*)d_out;

    float* gxbuf = (float*)d_ws;
    const size_t need = (size_t)NS * NB * NG * sizeof(float);  // ~50.3 MB
    const int use_gx = (d_ws != nullptr && ws_size >= need) ? 1 : 0;

    if (use_gx) {
        gx_kernel<<<NS, 384, 0, stream>>>(x, W_ih, b_ih, gxbuf);
    }
    prep_kernel<<<512, 128, 0, stream>>>(W1, W_hh, W2, b2);
    rnn_kernel<<<NB, 512, 0, stream>>>(times, b_hh, b1, b2,
                                       W_mean, b_mean, W_logvar, b_logvar,
                                       gxbuf, x, W_ih, b_ih, use_gx, out);
}